// Round 4
// baseline (267.398 us; speedup 1.0000x reference)
//
#include <hip/hip_runtime.h>
#include <hip/hip_fp16.h>
#include <cstdint>
#include <cstddef>

#define NQQ  (144*144)        // 20736
#define SCALE 0.17677669529663687f

// ws layout in HALF elements. Base 57,378,816 halves = 114.76 MB.
// Optional bias-precompute region appended: +7,962,624 halves -> 130.7 MB.
#define AOH   0ull
#define X16H  0ull
#define QH    14155776ull
#define KH    28311552ull
#define VH    42467328ull
#define WTH   56623104ull      // 442368 halves (1152x384)
#define WOTH  57065472ull      // 147456 halves (384x384)
#define MASKH 57212928ull      // 165888 halves (8x144x144 fp16)
#define BIASH 57378816ull      // 3072 x 2592 fp16 precomputed bias (optional)
#define WS_NEED_BYTES ((BIASH + 3072ull * 2592ull) * 2ull)

typedef _Float16 half8  __attribute__((ext_vector_type(8)));
typedef _Float16 half4v __attribute__((ext_vector_type(4)));
typedef float    f32x4  __attribute__((ext_vector_type(4)));

typedef __attribute__((address_space(1))) const unsigned int guint;
typedef __attribute__((address_space(3))) unsigned int luint;
#define GLD16(g, l) __builtin_amdgcn_global_load_lds((guint*)(g), (luint*)(l), 16, 0, 0)

// ---------------------------------------------------------------------------
// PREP: [0,13824) X fp32->fp16; [13824,13932) transpose w_qkv;
// [13932,13968) transpose w_out; [13968,14130) mask fp32->fp16;
// [14130,15426) OPTIONAL bias precompute (dense fp16 bias[bh][2592]).
// ---------------------------------------------------------------------------
__launch_bounds__(256)
__global__ void k_prep(const float* __restrict__ X, _Float16* __restrict__ X16,
                       const float* __restrict__ Wq, _Float16* __restrict__ WqT,
                       const float* __restrict__ Wo, _Float16* __restrict__ WoT,
                       const float* __restrict__ M, _Float16* __restrict__ M16,
                       const float* __restrict__ table, const int* __restrict__ pidx,
                       _Float16* __restrict__ biasOut) {
    __shared__ __align__(16) char psm[13888];
    const int bid = blockIdx.x;
    const int t   = threadIdx.x;
    if (bid < 13824) {
        size_t i = (size_t)bid * 256 + t;
        float4 f = *(const float4*)&X[i * 4];
        _Float16 h[4] = {(_Float16)f.x, (_Float16)f.y, (_Float16)f.z, (_Float16)f.w};
        *(ushort4*)&X16[i * 4] = *(ushort4*)h;
        return;
    }
    if (bid >= 14130) {
        // ---- bias precompute: block = (s_tile, chunk of 16 i-rows) ----
        _Float16 (*sTb)[18] = (_Float16(*)[18])psm;   // 384 x 18 halves = 13824 B
        int* rowsL = (int*)(psm + 13824);             // 16 ints
        const int j      = bid - 14130;
        const int s_tile = j / 162;
        const int chunk  = j - s_tile * 162;
        const int i0     = chunk * 16;
        if (t < 16) rowsL[t] = pidx[8 * (i0 + t) + s_tile];
        __syncthreads();
#pragma unroll
        for (int rr = 0; rr < 16; ++rr) {
            int row = rowsL[rr];
            sTb[t][rr] = (_Float16)table[(size_t)row * 384 + t];
            if (t < 128) sTb[t + 256][rr] = (_Float16)table[(size_t)row * 384 + t + 256];
        }
        __syncthreads();
        unsigned int* ob = (unsigned int*)biasOut;    // dword view of fp16 pairs
#pragma unroll
        for (int v = t; v < 3072; v += 256) {
            int i1h = v >> 3, dw = v & 7;             // bh = s_tile*384 + i1h
            ob[(size_t)(s_tile * 384 + i1h) * 1296 + chunk * 8 + dw] =
                *(const unsigned int*)&sTb[i1h][dw * 2];
        }
        return;
    }
    if (bid >= 13968) {
        size_t i = (size_t)(bid - 13968) * 256 + t;
        float4 f = *(const float4*)&M[i * 4];
        _Float16 h[4] = {(_Float16)f.x, (_Float16)f.y, (_Float16)f.z, (_Float16)f.w};
        *(ushort4*)&M16[i * 4] = *(ushort4*)h;
        return;
    }
    _Float16 (*sT)[72] = (_Float16(*)[72])psm;        // 64 x 72 halves = 9216 B
    const float* W; _Float16* WT; int K, Cn, cb, kb;
    if (bid < 13932) {
        int j = bid - 13824;
        W = Wq; WT = WqT; K = 384; Cn = 1152;
        cb = (j % 18) * 64; kb = (j / 18) * 64;
    } else {
        int j = bid - 13932;
        W = Wo; WT = WoT; K = 384; Cn = 384;
        cb = (j % 6) * 64; kb = (j / 6) * 64;
    }
#pragma unroll
    for (int i = 0; i < 16; ++i) {
        int id = t + 256 * i;
        int kl = id >> 6, cl = id & 63;
        sT[cl][kl] = (_Float16)W[(size_t)(kb + kl) * Cn + cb + cl];
    }
    __syncthreads();
#pragma unroll
    for (int i = 0; i < 16; ++i) {
        int id = t + 256 * i;
        int cl = id >> 6, kl = id & 63;
        WT[(size_t)(cb + cl) * K + kb + kl] = sT[cl][kl];
    }
}

// ---------------------------------------------------------------------------
// GEMM staging helpers (K1/K3 shared structure):
// BK=32 double-buffer. LDS layout per buffer: [128 rows][4 chunks of 16B],
// stored chunk pos = kchunk ^ ((row>>1)&3)  -> 2-way-max bank access on
// ds_read_b128 (free). Inverse swizzle applied on the GLOBAL source address;
// global_load_lds dests stay linear (rule: both-sides-or-neither).
// Per step: issue 4 GLD16 for NEXT buffer, then ds_read+MFMA current buffer,
// then one __syncthreads (vmcnt(0) drain overlapped with compute).
// ---------------------------------------------------------------------------
#define STAGE2(dA, dB, kk) do {                                   \
    GLD16(gA + (kk),          (char*)(dA) + t * 16);              \
    GLD16(gA + (kk) + 24576,  (char*)(dA) + t * 16 + 4096);       \
    GLD16(gB + (kk),          (char*)(dB) + t * 16);              \
    GLD16(gB + (kk) + 24576,  (char*)(dB) + t * 16 + 4096);       \
} while (0)

#define CSTEP(pA, pB) do {                                        \
    half8 a[4], b[4];                                             \
    _Pragma("unroll")                                             \
    for (int i = 0; i < 4; ++i) a[i] = *(const half8*)((pA) + i * 1024); \
    _Pragma("unroll")                                             \
    for (int j = 0; j < 4; ++j) b[j] = *(const half8*)((pB) + j * 1024); \
    _Pragma("unroll")                                             \
    for (int i = 0; i < 4; ++i)                                   \
    _Pragma("unroll")                                             \
        for (int j = 0; j < 4; ++j)                               \
            acc[i][j] = __builtin_amdgcn_mfma_f32_16x16x32_f16(a[i], b[j], acc[i][j], 0, 0, 0); \
} while (0)

// ---------------------------------------------------------------------------
// K1: qkv = X16 @ WT^T (+bias, scale q) -> scatter fp16 [bh][n][d].
// v3: BK=32 double-buffered pipeline (prefetch-before-compute).
// ---------------------------------------------------------------------------
__launch_bounds__(256)
__global__ void k_qkv_gemm_mfma(const _Float16* __restrict__ X16,
                                const _Float16* __restrict__ WT,
                                const float* __restrict__ bq,
                                _Float16* __restrict__ ws16) {
    __shared__ __align__(16) _Float16 sA0[4096], sB0[4096], sA1[4096], sB1[4096];
    const int t    = threadIdx.x;
    const int lane = t & 63;
    const int w    = t >> 6;
    const int quad = lane >> 4;
    const int l15  = lane & 15;
    // bijective XCD swizzle: 2592 = 8 * 324; col-tile fastest within chunk
    const int bid = blockIdx.x;
    const int wg  = (bid & 7) * 324 + (bid >> 3);
    const int cy  = wg % 9, rx = wg / 9;
    const int r0  = rx * 128, c0 = cy * 128;
    const int wr  = (w >> 1) * 64, wc = (w & 1) * 64;

    // staging source: 4 lanes per row; source k-chunk inverse-swizzled
    const int srow = t >> 2;
    const int skch = (t & 3) ^ ((t >> 3) & 3);
    const _Float16* gA = &X16[(size_t)(r0 + srow) * 384 + skch * 8];
    const _Float16* gB = &WT [(size_t)(c0 + srow) * 384 + skch * 8];

    // read-side: byte = row*64 + (quad ^ ((l15>>1)&3))*16, row = w{r,c}+16i+l15
    const int swz16 = (quad ^ ((l15 >> 1) & 3)) * 16;
    const char* rA0 = (const char*)sA0 + (wr + l15) * 64 + swz16;
    const char* rA1 = (const char*)sA1 + (wr + l15) * 64 + swz16;
    const char* rB0 = (const char*)sB0 + (wc + l15) * 64 + swz16;
    const char* rB1 = (const char*)sB1 + (wc + l15) * 64 + swz16;

    f32x4 acc[4][4] = {};

    STAGE2(sA0, sB0, 0);
    __syncthreads();
#pragma unroll
    for (int s2 = 0; s2 < 6; ++s2) {
        // even step: compute buf0 @ kk=64*s2, stage buf1 @ kk+32
        STAGE2(sA1, sB1, 64 * s2 + 32);
        CSTEP(rA0, rB0);
        __syncthreads();
        // odd step: compute buf1 @ kk=64*s2+32, stage buf0 @ kk+64
        if (s2 < 5) STAGE2(sA0, sB0, 64 * s2 + 64);
        CSTEP(rA1, rB1);
        __syncthreads();
    }

#pragma unroll
    for (int j = 0; j < 4; ++j) {
        int c  = c0 + wc + 16 * j + l15;
        int p  = c / 384;
        int hh = (c >> 5) % 12;
        int d0 = c & 31;
        float bias = bq[c];
        float sc   = (p == 0) ? SCALE : 1.0f;
        size_t base = (p == 0) ? QH : ((p == 1) ? KH : VH);
#pragma unroll
        for (int i = 0; i < 4; ++i) {
#pragma unroll
            for (int reg = 0; reg < 4; ++reg) {
                int r  = r0 + wr + 16 * i + quad * 4 + reg;
                int bw = r / 144;
                int n  = r - bw * 144;
                ws16[base + (((size_t)bw * 12 + hh) * 144 + n) * 32 + d0] =
                    (_Float16)((acc[i][j][reg] + bias) * sc);
            }
        }
    }
}

// ---------------------------------------------------------------------------
// K2: MFMA attention, S^T formulation — NO P round-trip through LDS.
// One (b,h) per block, 576 threads = 9 waves; wave w owns q-tile w.
// sBias stride 148 (2-way), sVT chunk-XOR swizzle (2-way), precomputed bias.
// LDS: sK 11520 + sVT 10752 + sBias 5328 = 27600 B. ONE barrier.
// ---------------------------------------------------------------------------
__launch_bounds__(576)
__global__ void k_attn_fused_mfma(const _Float16* __restrict__ ws16,
                                  const _Float16* __restrict__ mask16,
                                  const float* __restrict__ table,
                                  const int* __restrict__ pidx,
                                  const _Float16* __restrict__ bias_pre,
                                  _Float16* __restrict__ AO) {
    __shared__ __align__(16) char smem[27616];
    _Float16 (*sK)[40]   = (_Float16(*)[40])(smem);             // 11520
    _Float16 (*sVT)[168] = (_Float16(*)[168])(smem + 11520);    // 10752
    _Float16* sBias      = (_Float16*)(smem + 22272);           // 18*148*2 = 5328

    const int bh = blockIdx.x;
    const int b  = bh / 12;
    const int h  = bh - b * 12;
    const int t  = threadIdx.x;
    const int w    = t >> 6;        // 0..8 : q-tile index
    const int lane = t & 63;
    const int quad = lane >> 4;
    const int l15  = lane & 15;

    const int s_tile = b >> 5;
    const int i1     = b & 31;

    // --- phase 1: loads ---
    const _Float16* qg = ws16 + QH + (size_t)bh * 4608;
    const _Float16* kg = ws16 + KH + (size_t)bh * 4608;
    const _Float16* vg = ws16 + VH + (size_t)bh * 4608;

    half8 aq = *(const half8*)&qg[(size_t)(16 * w + l15) * 32 + quad * 8];

    {   // K: one uint4 per thread (144 rows x 4 chunks = 576)
        int row = t >> 2, ko = (t & 3) * 8;
        *(uint4*)&sK[row][ko] = *(const uint4*)&kg[row * 32 + ko];
    }
    for (int i = t; i < 2304; i += 576) {          // V -> V^T (chunk-XOR swizzled)
        unsigned int u = ((const unsigned int*)vg)[i];
        int m  = i >> 4, d0 = (i & 15) * 2;
        int mp = m ^ ((d0 >> 3) << 3);             // d0 even: d0,d0+1 share d0>>3
        sVT[d0][mp]     = ((const _Float16*)&u)[0];
        sVT[d0 + 1][mp] = ((const _Float16*)&u)[1];
    }
    if (t < 512) {                                 // V^T zero-pad cols 144..159
        int d = t & 31, m = 144 + (t >> 5);
        sVT[d][m ^ ((d >> 3) << 3)] = (_Float16)0;
    }
    if (bias_pre) {                                // contiguous precomputed bias
        const _Float16* bg = bias_pre + (size_t)bh * 2592;
        for (int i2 = t; i2 < 648; i2 += 576) {
            uint2 wv = *(const uint2*)&bg[i2 * 4];
            int r18 = i2 / 36;
            int col = i2 * 4 - r18 * 144;
            *(uint2*)&sBias[r18 * 148 + col] = wv;
        }
    } else {                                       // fallback: gather (padded rows)
        for (int i = t; i < 2592; i += 576) {
            int row = pidx[8 * i + s_tile];
            int r18 = i / 144;
            sBias[r18 * 148 + (i - r18 * 144)] =
                (_Float16)table[(size_t)row * 384 + i1 * 12 + h];
        }
    }
    __syncthreads();   // the ONLY barrier

    // --- phase 2: T_j = S^T tiles = mfma(K_j, Q_w) ---
    f32x4 tj[9] = {};
#pragma unroll
    for (int j = 0; j < 9; ++j) {
        half8 bk = *(const half8*)&sK[16 * j + l15][quad * 8];
        tj[j] = __builtin_amdgcn_mfma_f32_16x16x32_f16(bk, aq, tj[j], 0, 0, 0);
    }

    // --- phase 3: bias + mask + softmax over each query column ---
    const int q    = 16 * w + l15;                 // this lane's query row
    const int nb18 = q % 18;
    const _Float16* mrow = mask16 + (size_t)(b & 7) * NQQ + (size_t)q * 144 + 4 * quad;
    uint2 mz[9];
#pragma unroll
    for (int j = 0; j < 9; ++j) mz[j] = *(const uint2*)&mrow[16 * j];
#pragma unroll
    for (int j = 0; j < 9; ++j) {
        uint2 bz = *(const uint2*)&sBias[nb18 * 148 + 16 * j + 4 * quad];
        const _Float16* bb = (const _Float16*)&bz;
        const _Float16* mm = (const _Float16*)&mz[j];
#pragma unroll
        for (int reg = 0; reg < 4; ++reg)
            tj[j][reg] += (float)bb[reg] + (float)mm[reg];
    }
    float rmax = tj[0][0];
#pragma unroll
    for (int j = 0; j < 9; ++j)
#pragma unroll
        for (int reg = 0; reg < 4; ++reg) rmax = fmaxf(rmax, tj[j][reg]);
    rmax = fmaxf(rmax, __shfl_xor(rmax, 16));
    rmax = fmaxf(rmax, __shfl_xor(rmax, 32));
    float rsum = 0.0f;
#pragma unroll
    for (int j = 0; j < 9; ++j)
#pragma unroll
        for (int reg = 0; reg < 4; ++reg) {
            tj[j][reg] = __expf(tj[j][reg] - rmax);
            rsum += tj[j][reg];
        }
    rsum += __shfl_xor(rsum, 16);
    rsum += __shfl_xor(rsum, 32);
    const float inv = 1.0f / rsum;

    // pack P^T rows (scaled) to fp16 pairs; index 9 = zero pad (keys 144..159)
    unsigned int pkA[10], pkB[10];
    pkA[9] = 0u; pkB[9] = 0u;
#pragma unroll
    for (int j = 0; j < 9; ++j) {
        auto a2 = __builtin_amdgcn_cvt_pkrtz(tj[j][0] * inv, tj[j][1] * inv);
        auto b2 = __builtin_amdgcn_cvt_pkrtz(tj[j][2] * inv, tj[j][3] * inv);
        pkA[j] = *(unsigned int*)&a2;
        pkB[j] = *(unsigned int*)&b2;
    }

    // --- phase 4: O^T = V^T @ P^T ; P^T B-frags via cross-lane shuffles ---
    const int src_lo = 32 * (quad & 1) + l15;
    const int src_hi = src_lo + 16;
    const bool selhi = (quad >> 1) != 0;
    f32x4 o[2] = {};
#pragma unroll
    for (int kt = 0; kt < 5; ++kt) {
        const int j0 = 2 * kt, j1 = 2 * kt + 1;
        unsigned int a0l = __shfl((int)pkA[j0], src_lo);
        unsigned int a1l = __shfl((int)pkA[j1], src_lo);
        unsigned int b0l = __shfl((int)pkB[j0], src_lo);
        unsigned int b1l = __shfl((int)pkB[j1], src_lo);
        unsigned int a0h = __shfl((int)pkA[j0], src_hi);
        unsigned int a1h = __shfl((int)pkA[j1], src_hi);
        unsigned int b0h = __shfl((int)pkB[j0], src_hi);
        unsigned int b1h = __shfl((int)pkB[j1], src_hi);
        union { uint4 u4; half8 h8; } bp;
        bp.u4.x = selhi ? a1l : a0l;
        bp.u4.y = selhi ? b1l : b0l;
        bp.u4.z = selhi ? a1h : a0h;
        bp.u4.w = selhi ? b1h : b0h;
#pragma unroll
        for (int dt = 0; dt < 2; ++dt) {
            const int vrow = dt * 16 + l15;
            half8 av = *(const half8*)&sVT[vrow][(kt * 32 + quad * 8) ^ ((vrow >> 3) << 3)];
            o[dt] = __builtin_amdgcn_mfma_f32_16x16x32_f16(av, bp.h8, o[dt], 0, 0, 0);
        }
    }

    // --- stores: O^T[d][q] -> AO[b][q][h*32+d] ---
#pragma unroll
    for (int dt = 0; dt < 2; ++dt) {
        int d = dt * 16 + quad * 4;
        half4v hv;
#pragma unroll
        for (int reg = 0; reg < 4; ++reg) hv[reg] = (_Float16)o[dt][reg];
        *(half4v*)&AO[((size_t)b * 144 + q) * 384 + h * 32 + d] = hv;
    }
}

// ---------------------------------------------------------------------------
// K3: out = AO @ WoT^T + b_out. fp32 output. Same v3 pipeline as K1.
// ---------------------------------------------------------------------------
__launch_bounds__(256)
__global__ void k_out_gemm_mfma(const _Float16* __restrict__ A16,
                                const _Float16* __restrict__ WoT,
                                const float* __restrict__ bo,
                                float* __restrict__ out) {
    __shared__ __align__(16) _Float16 sA0[4096], sB0[4096], sA1[4096], sB1[4096];
    const int t    = threadIdx.x;
    const int lane = t & 63;
    const int w    = t >> 6;
    const int quad = lane >> 4;
    const int l15  = lane & 15;
    // bijective XCD swizzle: 864 = 8 * 108; col-tile fastest within chunk
    const int bid = blockIdx.x;
    const int wg  = (bid & 7) * 108 + (bid >> 3);
    const int cy  = wg % 3, rx = wg / 3;
    const int r0  = rx * 128, c0 = cy * 128;
    const int wr  = (w >> 1) * 64, wc = (w & 1) * 64;

    const int srow = t >> 2;
    const int skch = (t & 3) ^ ((t >> 3) & 3);
    const _Float16* gA = &A16[(size_t)(r0 + srow) * 384 + skch * 8];
    const _Float16* gB = &WoT[(size_t)(c0 + srow) * 384 + skch * 8];

    const int swz16 = (quad ^ ((l15 >> 1) & 3)) * 16;
    const char* rA0 = (const char*)sA0 + (wr + l15) * 64 + swz16;
    const char* rA1 = (const char*)sA1 + (wr + l15) * 64 + swz16;
    const char* rB0 = (const char*)sB0 + (wc + l15) * 64 + swz16;
    const char* rB1 = (const char*)sB1 + (wc + l15) * 64 + swz16;

    f32x4 acc[4][4] = {};

    STAGE2(sA0, sB0, 0);
    __syncthreads();
#pragma unroll
    for (int s2 = 0; s2 < 6; ++s2) {
        STAGE2(sA1, sB1, 64 * s2 + 32);
        CSTEP(rA0, rB0);
        __syncthreads();
        if (s2 < 5) STAGE2(sA0, sB0, 64 * s2 + 64);
        CSTEP(rA1, rB1);
        __syncthreads();
    }

#pragma unroll
    for (int j = 0; j < 4; ++j) {
        int c = c0 + wc + 16 * j + l15;
        float bias = bo[c];
#pragma unroll
        for (int i = 0; i < 4; ++i) {
#pragma unroll
            for (int reg = 0; reg < 4; ++reg) {
                int r = r0 + wr + 16 * i + quad * 4 + reg;
                out[(size_t)r * 384 + c] = acc[i][j][reg] + bias;
            }
        }
    }
}

// ---------------------------------------------------------------------------
extern "C" void kernel_launch(void* const* d_in, const int* in_sizes, int n_in,
                              void* d_out, int out_size, void* d_ws, size_t ws_size,
                              hipStream_t stream) {
    const float* x      = (const float*)d_in[0];
    const float* mask   = (const float*)d_in[1];
    const float* w_qkv  = (const float*)d_in[2];
    const float* b_qkv  = (const float*)d_in[3];
    const float* w_out  = (const float*)d_in[4];
    const float* b_out  = (const float*)d_in[5];
    const float* table  = (const float*)d_in[6];
    const int*   pidx   = (const int*)d_in[7];
    float* out = (float*)d_out;
    _Float16* ws16 = (_Float16*)d_ws;

    const bool pre = ws_size >= (size_t)WS_NEED_BYTES;
    _Float16* bias16 = pre ? (ws16 + BIASH) : (_Float16*)nullptr;

    hipLaunchKernelGGL(k_prep,          dim3(pre ? 15426 : 14130), dim3(256), 0, stream,
                       x, ws16 + X16H, w_qkv, ws16 + WTH, w_out, ws16 + WOTH,
                       mask, ws16 + MASKH, table, pidx, bias16);
    hipLaunchKernelGGL(k_qkv_gemm_mfma, dim3(2592), dim3(256), 0, stream,
                       ws16 + X16H, ws16 + WTH, b_qkv, ws16);
    hipLaunchKernelGGL(k_attn_fused_mfma, dim3(3072), dim3(576), 0, stream,
                       ws16, ws16 + MASKH, table, pidx, bias16, ws16 + AOH);
    hipLaunchKernelGGL(k_out_gemm_mfma, dim3(864), dim3(256), 0, stream,
                       ws16 + AOH, ws16 + WOTH, b_out, out);
}

// Round 5
// 259.419 us; speedup vs baseline: 1.0308x; 1.0308x over previous
//
#include <hip/hip_runtime.h>
#include <hip/hip_fp16.h>
#include <cstdint>
#include <cstddef>

#define NQQ  (144*144)        // 20736
#define SCALE 0.17677669529663687f

// ws layout in HALF elements. Base 57,378,816 halves = 114.76 MB.
// Optional bias-precompute region appended: +7,962,624 halves -> 130.7 MB.
#define AOH   0ull
#define X16H  0ull
#define QH    14155776ull
#define KH    28311552ull
#define VH    42467328ull
#define WTH   56623104ull      // 442368 halves (1152x384)
#define WOTH  57065472ull      // 147456 halves (384x384)
#define MASKH 57212928ull      // 165888 halves (8x144x144 fp16)
#define BIASH 57378816ull      // 3072 x 2592 fp16 precomputed bias (optional)
#define WS_NEED_BYTES ((BIASH + 3072ull * 2592ull) * 2ull)

typedef _Float16 half8  __attribute__((ext_vector_type(8)));
typedef _Float16 half4v __attribute__((ext_vector_type(4)));
typedef float    f32x4  __attribute__((ext_vector_type(4)));

typedef __attribute__((address_space(1))) const unsigned int guint;
typedef __attribute__((address_space(3))) unsigned int luint;
#define GLD16(g, l) __builtin_amdgcn_global_load_lds((guint*)(g), (luint*)(l), 16, 0, 0)

#define WAITV4 asm volatile("s_waitcnt vmcnt(4)" ::: "memory")
#define WAITV0 asm volatile("s_waitcnt vmcnt(0)" ::: "memory")

// ---------------------------------------------------------------------------
// PREP: [0,13824) X fp32->fp16; [13824,13932) transpose w_qkv;
// [13932,13968) transpose w_out; [13968,14130) mask fp32->fp16;
// [14130,15426) OPTIONAL bias precompute (dense fp16 bias[bh][2592]).
// ---------------------------------------------------------------------------
__launch_bounds__(256)
__global__ void k_prep(const float* __restrict__ X, _Float16* __restrict__ X16,
                       const float* __restrict__ Wq, _Float16* __restrict__ WqT,
                       const float* __restrict__ Wo, _Float16* __restrict__ WoT,
                       const float* __restrict__ M, _Float16* __restrict__ M16,
                       const float* __restrict__ table, const int* __restrict__ pidx,
                       _Float16* __restrict__ biasOut) {
    __shared__ __align__(16) char psm[13888];
    const int bid = blockIdx.x;
    const int t   = threadIdx.x;
    if (bid < 13824) {
        size_t i = (size_t)bid * 256 + t;
        float4 f = *(const float4*)&X[i * 4];
        _Float16 h[4] = {(_Float16)f.x, (_Float16)f.y, (_Float16)f.z, (_Float16)f.w};
        *(ushort4*)&X16[i * 4] = *(ushort4*)h;
        return;
    }
    if (bid >= 14130) {
        // ---- bias precompute: block = (s_tile, chunk of 16 i-rows) ----
        _Float16 (*sTb)[18] = (_Float16(*)[18])psm;   // 384 x 18 halves = 13824 B
        int* rowsL = (int*)(psm + 13824);             // 16 ints
        const int j      = bid - 14130;
        const int s_tile = j / 162;
        const int chunk  = j - s_tile * 162;
        const int i0     = chunk * 16;
        if (t < 16) rowsL[t] = pidx[8 * (i0 + t) + s_tile];
        __syncthreads();
#pragma unroll
        for (int rr = 0; rr < 16; ++rr) {
            int row = rowsL[rr];
            sTb[t][rr] = (_Float16)table[(size_t)row * 384 + t];
            if (t < 128) sTb[t + 256][rr] = (_Float16)table[(size_t)row * 384 + t + 256];
        }
        __syncthreads();
        unsigned int* ob = (unsigned int*)biasOut;    // dword view of fp16 pairs
#pragma unroll
        for (int v = t; v < 3072; v += 256) {
            int i1h = v >> 3, dw = v & 7;             // bh = s_tile*384 + i1h
            ob[(size_t)(s_tile * 384 + i1h) * 1296 + chunk * 8 + dw] =
                *(const unsigned int*)&sTb[i1h][dw * 2];
        }
        return;
    }
    if (bid >= 13968) {
        size_t i = (size_t)(bid - 13968) * 256 + t;
        float4 f = *(const float4*)&M[i * 4];
        _Float16 h[4] = {(_Float16)f.x, (_Float16)f.y, (_Float16)f.z, (_Float16)f.w};
        *(ushort4*)&M16[i * 4] = *(ushort4*)h;
        return;
    }
    _Float16 (*sT)[72] = (_Float16(*)[72])psm;        // 64 x 72 halves = 9216 B
    const float* W; _Float16* WT; int K, Cn, cb, kb;
    if (bid < 13932) {
        int j = bid - 13824;
        W = Wq; WT = WqT; K = 384; Cn = 1152;
        cb = (j % 18) * 64; kb = (j / 18) * 64;
    } else {
        int j = bid - 13932;
        W = Wo; WT = WoT; K = 384; Cn = 384;
        cb = (j % 6) * 64; kb = (j / 6) * 64;
    }
#pragma unroll
    for (int i = 0; i < 16; ++i) {
        int id = t + 256 * i;
        int kl = id >> 6, cl = id & 63;
        sT[cl][kl] = (_Float16)W[(size_t)(kb + kl) * Cn + cb + cl];
    }
    __syncthreads();
#pragma unroll
    for (int i = 0; i < 16; ++i) {
        int id = t + 256 * i;
        int cl = id >> 6, kl = id & 63;
        WT[(size_t)(cb + cl) * K + kb + kl] = sT[cl][kl];
    }
}

// ---------------------------------------------------------------------------
// GEMM pipeline (K1/K3 shared): BK=32, THREE buffers, stage depth 2,
// counted vmcnt + RAW s_barrier (T4) so prefetch loads stay in flight
// ACROSS barriers (never drain to 0 in the main loop).
// Per chunk stage = 4 GLD16/thread (A half0/half1, B half0/half1).
// LDS layout per buffer: [128 rows][4 chunks 16B], stored chunk
// pos = q ^ ((row>>1)&3); inverse applied on GLOBAL source (rule #21).
// Iter s: vmcnt(4) [chunk s landed, chunk s+1 still in flight] -> barrier
// -> issue stage s+2 -> ds_read+16 MFMA on buffer s%3.
// ---------------------------------------------------------------------------
#define STAGE3(dA, dB, kk) do {                                   \
    GLD16(gA + (kk),          (char*)(dA) + t * 16);              \
    GLD16(gA + (kk) + 24576,  (char*)(dA) + t * 16 + 4096);       \
    GLD16(gB + (kk),          (char*)(dB) + t * 16);              \
    GLD16(gB + (kk) + 24576,  (char*)(dB) + t * 16 + 4096);       \
} while (0)

#define CSTEP(pA, pB) do {                                        \
    half8 a[4], b[4];                                             \
    _Pragma("unroll")                                             \
    for (int i = 0; i < 4; ++i) a[i] = *(const half8*)((pA) + i * 1024); \
    _Pragma("unroll")                                             \
    for (int j = 0; j < 4; ++j) b[j] = *(const half8*)((pB) + j * 1024); \
    _Pragma("unroll")                                             \
    for (int i = 0; i < 4; ++i)                                   \
    _Pragma("unroll")                                             \
        for (int j = 0; j < 4; ++j)                               \
            acc[i][j] = __builtin_amdgcn_mfma_f32_16x16x32_f16(a[i], b[j], acc[i][j], 0, 0, 0); \
} while (0)

#define GEMM_PIPE() do {                                          \
    STAGE3(sA[0], sB[0], 0);                                      \
    STAGE3(sA[1], sB[1], 32);                                     \
    _Pragma("unroll")                                             \
    for (int s = 0; s < 12; ++s) {                                \
        if (s < 11) { WAITV4; } else { WAITV0; }                  \
        __builtin_amdgcn_s_barrier();                             \
        if (s < 10) STAGE3(sA[(s + 2) % 3], sB[(s + 2) % 3], 32 * (s + 2)); \
        const char* pA = (const char*)sA[s % 3] + aoff;           \
        const char* pB = (const char*)sB[s % 3] + boff;           \
        CSTEP(pA, pB);                                            \
    }                                                             \
} while (0)

// ---------------------------------------------------------------------------
// K1: qkv = X16 @ WT^T (+bias, scale q) -> scatter fp16 [bh][n][d].
// v4: T4 counted-vmcnt 3-buffer pipeline.
// ---------------------------------------------------------------------------
__launch_bounds__(256)
__global__ void k_qkv_gemm_mfma(const _Float16* __restrict__ X16,
                                const _Float16* __restrict__ WT,
                                const float* __restrict__ bq,
                                _Float16* __restrict__ ws16) {
    __shared__ __align__(16) _Float16 sA[3][4096];
    __shared__ __align__(16) _Float16 sB[3][4096];
    const int t    = threadIdx.x;
    const int lane = t & 63;
    const int w    = t >> 6;
    const int quad = lane >> 4;
    const int l15  = lane & 15;
    // bijective XCD swizzle: 2592 = 8 * 324; col-tile fastest within chunk
    const int bid = blockIdx.x;
    const int wg  = (bid & 7) * 324 + (bid >> 3);
    const int cy  = wg % 9, rx = wg / 9;
    const int r0  = rx * 128, c0 = cy * 128;
    const int wr  = (w >> 1) * 64, wc = (w & 1) * 64;

    // staging source: 4 lanes per row; source k-chunk inverse-swizzled
    const int srow = t >> 2;
    const int skch = (t & 3) ^ ((t >> 3) & 3);
    const _Float16* gA = &X16[(size_t)(r0 + srow) * 384 + skch * 8];
    const _Float16* gB = &WT [(size_t)(c0 + srow) * 384 + skch * 8];

    // read-side: byte = row*64 + (quad ^ ((l15>>1)&3))*16
    const int swz16 = (quad ^ ((l15 >> 1) & 3)) * 16;
    const int aoff  = (wr + l15) * 64 + swz16;
    const int boff  = (wc + l15) * 64 + swz16;

    f32x4 acc[4][4] = {};

    GEMM_PIPE();

#pragma unroll
    for (int j = 0; j < 4; ++j) {
        int c  = c0 + wc + 16 * j + l15;
        int p  = c / 384;
        int hh = (c >> 5) % 12;
        int d0 = c & 31;
        float bias = bq[c];
        float sc   = (p == 0) ? SCALE : 1.0f;
        size_t base = (p == 0) ? QH : ((p == 1) ? KH : VH);
#pragma unroll
        for (int i = 0; i < 4; ++i) {
#pragma unroll
            for (int reg = 0; reg < 4; ++reg) {
                int r  = r0 + wr + 16 * i + quad * 4 + reg;
                int bw = r / 144;
                int n  = r - bw * 144;
                ws16[base + (((size_t)bw * 12 + hh) * 144 + n) * 32 + d0] =
                    (_Float16)((acc[i][j][reg] + bias) * sc);
            }
        }
    }
}

// ---------------------------------------------------------------------------
// K2: MFMA attention, S^T formulation — NO P round-trip through LDS.
// One (b,h) per block, 576 threads = 9 waves; wave w owns q-tile w.
// sBias stride 148 (2-way), sVT chunk-XOR swizzle (2-way), precomputed bias.
// LDS: sK 11520 + sVT 10752 + sBias 5328 = 27600 B. ONE barrier.
// ---------------------------------------------------------------------------
__launch_bounds__(576)
__global__ void k_attn_fused_mfma(const _Float16* __restrict__ ws16,
                                  const _Float16* __restrict__ mask16,
                                  const float* __restrict__ table,
                                  const int* __restrict__ pidx,
                                  const _Float16* __restrict__ bias_pre,
                                  _Float16* __restrict__ AO) {
    __shared__ __align__(16) char smem[27616];
    _Float16 (*sK)[40]   = (_Float16(*)[40])(smem);             // 11520
    _Float16 (*sVT)[168] = (_Float16(*)[168])(smem + 11520);    // 10752
    _Float16* sBias      = (_Float16*)(smem + 22272);           // 18*148*2 = 5328

    const int bh = blockIdx.x;
    const int b  = bh / 12;
    const int h  = bh - b * 12;
    const int t  = threadIdx.x;
    const int w    = t >> 6;        // 0..8 : q-tile index
    const int lane = t & 63;
    const int quad = lane >> 4;
    const int l15  = lane & 15;

    const int s_tile = b >> 5;
    const int i1     = b & 31;

    // --- phase 1: loads ---
    const _Float16* qg = ws16 + QH + (size_t)bh * 4608;
    const _Float16* kg = ws16 + KH + (size_t)bh * 4608;
    const _Float16* vg = ws16 + VH + (size_t)bh * 4608;

    half8 aq = *(const half8*)&qg[(size_t)(16 * w + l15) * 32 + quad * 8];

    {   // K: one uint4 per thread (144 rows x 4 chunks = 576)
        int row = t >> 2, ko = (t & 3) * 8;
        *(uint4*)&sK[row][ko] = *(const uint4*)&kg[row * 32 + ko];
    }
    for (int i = t; i < 2304; i += 576) {          // V -> V^T (chunk-XOR swizzled)
        unsigned int u = ((const unsigned int*)vg)[i];
        int m  = i >> 4, d0 = (i & 15) * 2;
        int mp = m ^ ((d0 >> 3) << 3);             // d0 even: d0,d0+1 share d0>>3
        sVT[d0][mp]     = ((const _Float16*)&u)[0];
        sVT[d0 + 1][mp] = ((const _Float16*)&u)[1];
    }
    if (t < 512) {                                 // V^T zero-pad cols 144..159
        int d = t & 31, m = 144 + (t >> 5);
        sVT[d][m ^ ((d >> 3) << 3)] = (_Float16)0;
    }
    if (bias_pre) {                                // contiguous precomputed bias
        const _Float16* bg = bias_pre + (size_t)bh * 2592;
        for (int i2 = t; i2 < 648; i2 += 576) {
            uint2 wv = *(const uint2*)&bg[i2 * 4];
            int r18 = i2 / 36;
            int col = i2 * 4 - r18 * 144;
            *(uint2*)&sBias[r18 * 148 + col] = wv;
        }
    } else {                                       // fallback: gather (padded rows)
        for (int i = t; i < 2592; i += 576) {
            int row = pidx[8 * i + s_tile];
            int r18 = i / 144;
            sBias[r18 * 148 + (i - r18 * 144)] =
                (_Float16)table[(size_t)row * 384 + i1 * 12 + h];
        }
    }
    __syncthreads();   // the ONLY barrier

    // --- phase 2: T_j = S^T tiles = mfma(K_j, Q_w) ---
    f32x4 tj[9] = {};
#pragma unroll
    for (int j = 0; j < 9; ++j) {
        half8 bk = *(const half8*)&sK[16 * j + l15][quad * 8];
        tj[j] = __builtin_amdgcn_mfma_f32_16x16x32_f16(bk, aq, tj[j], 0, 0, 0);
    }

    // --- phase 3: bias + mask + softmax over each query column ---
    const int q    = 16 * w + l15;                 // this lane's query row
    const int nb18 = q % 18;
    const _Float16* mrow = mask16 + (size_t)(b & 7) * NQQ + (size_t)q * 144 + 4 * quad;
    uint2 mz[9];
#pragma unroll
    for (int j = 0; j < 9; ++j) mz[j] = *(const uint2*)&mrow[16 * j];
#pragma unroll
    for (int j = 0; j < 9; ++j) {
        uint2 bz = *(const uint2*)&sBias[nb18 * 148 + 16 * j + 4 * quad];
        const _Float16* bb = (const _Float16*)&bz;
        const _Float16* mm = (const _Float16*)&mz[j];
#pragma unroll
        for (int reg = 0; reg < 4; ++reg)
            tj[j][reg] += (float)bb[reg] + (float)mm[reg];
    }
    float rmax = tj[0][0];
#pragma unroll
    for (int j = 0; j < 9; ++j)
#pragma unroll
        for (int reg = 0; reg < 4; ++reg) rmax = fmaxf(rmax, tj[j][reg]);
    rmax = fmaxf(rmax, __shfl_xor(rmax, 16));
    rmax = fmaxf(rmax, __shfl_xor(rmax, 32));
    float rsum = 0.0f;
#pragma unroll
    for (int j = 0; j < 9; ++j)
#pragma unroll
        for (int reg = 0; reg < 4; ++reg) {
            tj[j][reg] = __expf(tj[j][reg] - rmax);
            rsum += tj[j][reg];
        }
    rsum += __shfl_xor(rsum, 16);
    rsum += __shfl_xor(rsum, 32);
    const float inv = 1.0f / rsum;

    // pack P^T rows (scaled) to fp16 pairs; index 9 = zero pad (keys 144..159)
    unsigned int pkA[10], pkB[10];
    pkA[9] = 0u; pkB[9] = 0u;
#pragma unroll
    for (int j = 0; j < 9; ++j) {
        auto a2 = __builtin_amdgcn_cvt_pkrtz(tj[j][0] * inv, tj[j][1] * inv);
        auto b2 = __builtin_amdgcn_cvt_pkrtz(tj[j][2] * inv, tj[j][3] * inv);
        pkA[j] = *(unsigned int*)&a2;
        pkB[j] = *(unsigned int*)&b2;
    }

    // --- phase 4: O^T = V^T @ P^T ; P^T B-frags via cross-lane shuffles ---
    const int src_lo = 32 * (quad & 1) + l15;
    const int src_hi = src_lo + 16;
    const bool selhi = (quad >> 1) != 0;
    f32x4 o[2] = {};
#pragma unroll
    for (int kt = 0; kt < 5; ++kt) {
        const int j0 = 2 * kt, j1 = 2 * kt + 1;
        unsigned int a0l = __shfl((int)pkA[j0], src_lo);
        unsigned int a1l = __shfl((int)pkA[j1], src_lo);
        unsigned int b0l = __shfl((int)pkB[j0], src_lo);
        unsigned int b1l = __shfl((int)pkB[j1], src_lo);
        unsigned int a0h = __shfl((int)pkA[j0], src_hi);
        unsigned int a1h = __shfl((int)pkA[j1], src_hi);
        unsigned int b0h = __shfl((int)pkB[j0], src_hi);
        unsigned int b1h = __shfl((int)pkB[j1], src_hi);
        union { uint4 u4; half8 h8; } bp;
        bp.u4.x = selhi ? a1l : a0l;
        bp.u4.y = selhi ? b1l : b0l;
        bp.u4.z = selhi ? a1h : a0h;
        bp.u4.w = selhi ? b1h : b0h;
#pragma unroll
        for (int dt = 0; dt < 2; ++dt) {
            const int vrow = dt * 16 + l15;
            half8 av = *(const half8*)&sVT[vrow][(kt * 32 + quad * 8) ^ ((vrow >> 3) << 3)];
            o[dt] = __builtin_amdgcn_mfma_f32_16x16x32_f16(av, bp.h8, o[dt], 0, 0, 0);
        }
    }

    // --- stores: O^T[d][q] -> AO[b][q][h*32+d] ---
#pragma unroll
    for (int dt = 0; dt < 2; ++dt) {
        int d = dt * 16 + quad * 4;
        half4v hv;
#pragma unroll
        for (int reg = 0; reg < 4; ++reg) hv[reg] = (_Float16)o[dt][reg];
        *(half4v*)&AO[((size_t)b * 144 + q) * 384 + h * 32 + d] = hv;
    }
}

// ---------------------------------------------------------------------------
// K3: out = AO @ WoT^T + b_out. fp32 output. Same v4 pipeline as K1.
// ---------------------------------------------------------------------------
__launch_bounds__(256)
__global__ void k_out_gemm_mfma(const _Float16* __restrict__ A16,
                                const _Float16* __restrict__ WoT,
                                const float* __restrict__ bo,
                                float* __restrict__ out) {
    __shared__ __align__(16) _Float16 sA[3][4096];
    __shared__ __align__(16) _Float16 sB[3][4096];
    const int t    = threadIdx.x;
    const int lane = t & 63;
    const int w    = t >> 6;
    const int quad = lane >> 4;
    const int l15  = lane & 15;
    // bijective XCD swizzle: 864 = 8 * 108; col-tile fastest within chunk
    const int bid = blockIdx.x;
    const int wg  = (bid & 7) * 108 + (bid >> 3);
    const int cy  = wg % 3, rx = wg / 3;
    const int r0  = rx * 128, c0 = cy * 128;
    const int wr  = (w >> 1) * 64, wc = (w & 1) * 64;

    const int srow = t >> 2;
    const int skch = (t & 3) ^ ((t >> 3) & 3);
    const _Float16* gA = &A16[(size_t)(r0 + srow) * 384 + skch * 8];
    const _Float16* gB = &WoT[(size_t)(c0 + srow) * 384 + skch * 8];

    const int swz16 = (quad ^ ((l15 >> 1) & 3)) * 16;
    const int aoff  = (wr + l15) * 64 + swz16;
    const int boff  = (wc + l15) * 64 + swz16;

    f32x4 acc[4][4] = {};

    GEMM_PIPE();

#pragma unroll
    for (int j = 0; j < 4; ++j) {
        int c = c0 + wc + 16 * j + l15;
        float bias = bo[c];
#pragma unroll
        for (int i = 0; i < 4; ++i) {
#pragma unroll
            for (int reg = 0; reg < 4; ++reg) {
                int r = r0 + wr + 16 * i + quad * 4 + reg;
                out[(size_t)r * 384 + c] = acc[i][j][reg] + bias;
            }
        }
    }
}

// ---------------------------------------------------------------------------
extern "C" void kernel_launch(void* const* d_in, const int* in_sizes, int n_in,
                              void* d_out, int out_size, void* d_ws, size_t ws_size,
                              hipStream_t stream) {
    const float* x      = (const float*)d_in[0];
    const float* mask   = (const float*)d_in[1];
    const float* w_qkv  = (const float*)d_in[2];
    const float* b_qkv  = (const float*)d_in[3];
    const float* w_out  = (const float*)d_in[4];
    const float* b_out  = (const float*)d_in[5];
    const float* table  = (const float*)d_in[6];
    const int*   pidx   = (const int*)d_in[7];
    float* out = (float*)d_out;
    _Float16* ws16 = (_Float16*)d_ws;

    const bool pre = ws_size >= (size_t)WS_NEED_BYTES;
    _Float16* bias16 = pre ? (ws16 + BIASH) : (_Float16*)nullptr;

    hipLaunchKernelGGL(k_prep,          dim3(pre ? 15426 : 14130), dim3(256), 0, stream,
                       x, ws16 + X16H, w_qkv, ws16 + WTH, w_out, ws16 + WOTH,
                       mask, ws16 + MASKH, table, pidx, bias16);
    hipLaunchKernelGGL(k_qkv_gemm_mfma, dim3(2592), dim3(256), 0, stream,
                       ws16 + X16H, ws16 + WTH, b_qkv, ws16);
    hipLaunchKernelGGL(k_attn_fused_mfma, dim3(3072), dim3(576), 0, stream,
                       ws16, ws16 + MASKH, table, pidx, bias16, ws16 + AOH);
    hipLaunchKernelGGL(k_out_gemm_mfma, dim3(864), dim3(256), 0, stream,
                       ws16 + AOH, ws16 + WOTH, b_out, out);
}

// Round 8
// 245.051 us; speedup vs baseline: 1.0912x; 1.0586x over previous
//
#include <hip/hip_runtime.h>
#include <hip/hip_fp16.h>
#include <cstdint>
#include <cstddef>

#define NQQ  (144*144)        // 20736
#define SCALE 0.17677669529663687f

// ws layout in HALF elements.
// X16 [0, 14155776) ; AO [QH, QH+14155776) (must NOT alias X16 — fused kernel
// reads X16 while writing AO).
#define X16H  0ull
#define QH    14155776ull      // = AO region for K3
#define WTH   56623104ull      // 442368 halves (1152x384)
#define WOTH  57065472ull      // 147456 halves (384x384)
#define MASKH 57212928ull      // 165888 halves (8x144x144 fp16)
#define BIASH 57378816ull      // 3072 x 2592 fp16 precomputed bias (optional)
#define WS_NEED_BYTES ((BIASH + 3072ull * 2592ull) * 2ull)

typedef _Float16 half8  __attribute__((ext_vector_type(8)));
typedef _Float16 half4v __attribute__((ext_vector_type(4)));
typedef float    f32x4  __attribute__((ext_vector_type(4)));

typedef __attribute__((address_space(1))) const unsigned int guint;
typedef __attribute__((address_space(3))) unsigned int luint;
#define GLD16(g, l) __builtin_amdgcn_global_load_lds((guint*)(g), (luint*)(l), 16, 0, 0)

#define WAITV4 asm volatile("s_waitcnt vmcnt(4)" ::: "memory")
#define WAITV0 asm volatile("s_waitcnt vmcnt(0)" ::: "memory")

// ---------------------------------------------------------------------------
// PREP: [0,13824) X fp32->fp16; [13824,13932) transpose w_qkv;
// [13932,13968) transpose w_out; [13968,14130) mask fp32->fp16;
// [14130,15426) OPTIONAL bias precompute (dense fp16 bias[bh][2592]).
// ---------------------------------------------------------------------------
__launch_bounds__(256)
__global__ void k_prep(const float* __restrict__ X, _Float16* __restrict__ X16,
                       const float* __restrict__ Wq, _Float16* __restrict__ WqT,
                       const float* __restrict__ Wo, _Float16* __restrict__ WoT,
                       const float* __restrict__ M, _Float16* __restrict__ M16,
                       const float* __restrict__ table, const int* __restrict__ pidx,
                       _Float16* __restrict__ biasOut) {
    __shared__ __align__(16) char psm[13888];
    const int bid = blockIdx.x;
    const int t   = threadIdx.x;
    if (bid < 13824) {
        size_t i = (size_t)bid * 256 + t;
        float4 f = *(const float4*)&X[i * 4];
        _Float16 h[4] = {(_Float16)f.x, (_Float16)f.y, (_Float16)f.z, (_Float16)f.w};
        *(ushort4*)&X16[i * 4] = *(ushort4*)h;
        return;
    }
    if (bid >= 14130) {
        // ---- bias precompute: block = (s_tile, chunk of 16 i-rows) ----
        _Float16 (*sTb)[18] = (_Float16(*)[18])psm;   // 384 x 18 halves = 13824 B
        int* rowsL = (int*)(psm + 13824);             // 16 ints
        const int j      = bid - 14130;
        const int s_tile = j / 162;
        const int chunk  = j - s_tile * 162;
        const int i0     = chunk * 16;
        if (t < 16) rowsL[t] = pidx[8 * (i0 + t) + s_tile];
        __syncthreads();
#pragma unroll
        for (int rr = 0; rr < 16; ++rr) {
            int row = rowsL[rr];
            sTb[t][rr] = (_Float16)table[(size_t)row * 384 + t];
            if (t < 128) sTb[t + 256][rr] = (_Float16)table[(size_t)row * 384 + t + 256];
        }
        __syncthreads();
        unsigned int* ob = (unsigned int*)biasOut;    // dword view of fp16 pairs
#pragma unroll
        for (int v = t; v < 3072; v += 256) {
            int i1h = v >> 3, dw = v & 7;             // bh = s_tile*384 + i1h
            ob[(size_t)(s_tile * 384 + i1h) * 1296 + chunk * 8 + dw] =
                *(const unsigned int*)&sTb[i1h][dw * 2];
        }
        return;
    }
    if (bid >= 13968) {
        size_t i = (size_t)(bid - 13968) * 256 + t;
        float4 f = *(const float4*)&M[i * 4];
        _Float16 h[4] = {(_Float16)f.x, (_Float16)f.y, (_Float16)f.z, (_Float16)f.w};
        *(ushort4*)&M16[i * 4] = *(ushort4*)h;
        return;
    }
    _Float16 (*sT)[72] = (_Float16(*)[72])psm;        // 64 x 72 halves = 9216 B
    const float* W; _Float16* WT; int K, Cn, cb, kb;
    if (bid < 13932) {
        int j = bid - 13824;
        W = Wq; WT = WqT; K = 384; Cn = 1152;
        cb = (j % 18) * 64; kb = (j / 18) * 64;
    } else {
        int j = bid - 13932;
        W = Wo; WT = WoT; K = 384; Cn = 384;
        cb = (j % 6) * 64; kb = (j / 6) * 64;
    }
#pragma unroll
    for (int i = 0; i < 16; ++i) {
        int id = t + 256 * i;
        int kl = id >> 6, cl = id & 63;
        sT[cl][kl] = (_Float16)W[(size_t)(kb + kl) * Cn + cb + cl];
    }
    __syncthreads();
#pragma unroll
    for (int i = 0; i < 16; ++i) {
        int id = t + 256 * i;
        int cl = id >> 6, kl = id & 63;
        WT[(size_t)(cb + cl) * K + kb + kl] = sT[cl][kl];
    }
}

// ---------------------------------------------------------------------------
// FUSED K1+K2: per (b,h) block — QKV GEMM (144x96 = X16[b] @ Wh^T), epilogue
// straight into LDS attn layouts (sQ/sK/sVT), then the verified attn phases
// 2-4. QKV never touches HBM.
// v3 of the fusion: ONE-LINE FIX of the rounds-6/7 bug — `srow & 95` is NOT
// identity on [0,96) (95 = 0b1011111, bit5 clear), so B-staging rows 32..63
// (the K weight strip) loaded Q's weight columns -> K was computed with Q's
// weights (deterministic absmax 5.9e-2 in both rounds). Fix: srB = srow
// (guarded). GEMM keeps the round-4-verified __syncthreads double-buffer.
// LDS 39120 B: dbufs A0/A1 [0,18432), B0/B1 [18432,30720);
// aliased post-GEMM: sQ [0,11520) sK [11520,23040) sVT [23040,33792);
// sBias [33792,39120).
// ---------------------------------------------------------------------------
__launch_bounds__(576)
__global__ void k_fused_qkv_attn(const _Float16* __restrict__ X16,
                                 const _Float16* __restrict__ WT,
                                 const float* __restrict__ bq,
                                 const _Float16* __restrict__ mask16,
                                 const float* __restrict__ table,
                                 const int* __restrict__ pidx,
                                 const _Float16* __restrict__ bias_pre,
                                 _Float16* __restrict__ AO) {
    __shared__ __align__(16) char smem[39120];
    _Float16 (*sQ)[40]   = (_Float16(*)[40])(smem);
    _Float16 (*sK)[40]   = (_Float16(*)[40])(smem + 11520);
    _Float16 (*sVT)[168] = (_Float16(*)[168])(smem + 23040);
    _Float16* sBias      = (_Float16*)(smem + 33792);  // 18*148*2 = 5328

    const int bid = blockIdx.x;
    const int wg  = (bid & 7) * 384 + (bid >> 3);  // 3072 = 8*384: same-b -> same XCD
    const int b   = wg / 12;
    const int h   = wg - b * 12;
    const int t   = threadIdx.x;
    const int w    = t >> 6;        // 0..8 : q-tile index / GEMM row-tile
    const int lane = t & 63;
    const int quad = lane >> 4;
    const int l15  = lane & 15;

    const int s_tile = b >> 5;
    const int i1     = b & 31;

    // staging geometry (identical swizzle family to the verified v2/v4 GEMMs)
    const int srow = t >> 2;                       // A: 144 rows x 4 chunks = 576
    const int schk = (t & 3) ^ ((t >> 3) & 3);     // inverse-swizzled source chunk
    const _Float16* gA = &X16[((size_t)b * 144 + srow) * 384 + schk * 8];
    const int srB  = (srow < 96) ? srow : 0;       // B: 96 rows (t<384 stage it)
    const int prow = (srB >> 5) * 384 + h * 32 + (srB & 31);
    const _Float16* gB = &WT[(size_t)prow * 384 + schk * 8];
    const int swz16 = (quad ^ ((l15 >> 1) & 3)) * 16;
    const int aoff  = (16 * w + l15) * 64 + swz16;

    // ---- prologue: bias -> sBias (drained by the first __syncthreads) ----
    if (bias_pre) {
        const _Float16* bg = bias_pre + (size_t)wg * 2592;
        for (int i2 = t; i2 < 648; i2 += 576) {
            uint2 wv = *(const uint2*)&bg[i2 * 4];
            int r18 = i2 / 36;
            int col = i2 * 4 - r18 * 144;
            *(uint2*)&sBias[r18 * 148 + col] = wv;
        }
    } else {
        for (int i = t; i < 2592; i += 576) {
            int row = pidx[8 * i + s_tile];
            int r18 = i / 144;
            sBias[r18 * 148 + (i - r18 * 144)] =
                (_Float16)table[(size_t)row * 384 + i1 * 12 + h];
        }
    }

    // ---- GEMM: acc[j] = D[row=16w+quad*4+reg][col=16j+l15], j=0..5 ----
    f32x4 acc[6] = {};
#define FSTG(s_) do {                                                      \
        GLD16(gA + 32 * (s_), smem + ((s_) & 1) * 9216 + t * 16);          \
        if (t < 384) GLD16(gB + 32 * (s_), smem + 18432 + ((s_) & 1) * 6144 + t * 16); \
    } while (0)
    FSTG(0);
    __syncthreads();   // buf0 staged (vmcnt+lgkm drained by syncthreads)
#pragma unroll
    for (int s = 0; s < 12; ++s) {
        if (s < 11) FSTG(s + 1);                   // stage next buffer
        const char* pA = smem + (s & 1) * 9216 + aoff;
        half8 av = *(const half8*)pA;
        const char* pB = smem + 18432 + (s & 1) * 6144;
#pragma unroll
        for (int j = 0; j < 6; ++j) {
            half8 bv = *(const half8*)(pB + (16 * j + l15) * 64 + swz16);
            acc[j] = __builtin_amdgcn_mfma_f32_16x16x32_f16(av, bv, acc[j], 0, 0, 0);
        }
        __syncthreads();                           // next buf landed; cur reads done
    }
#undef FSTG

    // ---- epilogue: QKV -> LDS attn layouts (+bias, Q scaled) ----
    float bqv[6];
#pragma unroll
    for (int j = 0; j < 6; ++j)
        bqv[j] = bq[(j >> 1) * 384 + h * 32 + (j & 1) * 16 + l15];
    const int erow = 16 * w + quad * 4;
#pragma unroll
    for (int j = 0; j < 2; ++j)
#pragma unroll
        for (int reg = 0; reg < 4; ++reg)
            sQ[erow + reg][16 * j + l15] = (_Float16)((acc[j][reg] + bqv[j]) * SCALE);
#pragma unroll
    for (int j = 0; j < 2; ++j)
#pragma unroll
        for (int reg = 0; reg < 4; ++reg)
            sK[erow + reg][16 * j + l15] = (_Float16)(acc[2 + j][reg] + bqv[2 + j]);
#pragma unroll
    for (int j = 0; j < 2; ++j) {
        const int d   = 16 * j + l15;
        const int dsw = (d >> 3) << 3;
#pragma unroll
        for (int reg = 0; reg < 4; ++reg)
            sVT[d][(erow + reg) ^ dsw] = (_Float16)(acc[4 + j][reg] + bqv[4 + j]);
    }
    if (t < 512) {                                 // V^T zero-pad cols 144..159
        int d = t & 31, m = 144 + (t >> 5);
        sVT[d][m ^ ((d >> 3) << 3)] = (_Float16)0;
    }
    __syncthreads();

    // ---- phase 2: T_j = S^T tiles = mfma(K_j, Q_w) ----
    half8 aq = *(const half8*)&sQ[16 * w + l15][quad * 8];
    f32x4 tj[9] = {};
#pragma unroll
    for (int j = 0; j < 9; ++j) {
        half8 bk = *(const half8*)&sK[16 * j + l15][quad * 8];
        tj[j] = __builtin_amdgcn_mfma_f32_16x16x32_f16(bk, aq, tj[j], 0, 0, 0);
    }

    // ---- phase 3: bias + mask + softmax over each query column ----
    const int q    = 16 * w + l15;
    const int nb18 = q % 18;
    const _Float16* mrow = mask16 + (size_t)(b & 7) * NQQ + (size_t)q * 144 + 4 * quad;
    uint2 mz[9];
#pragma unroll
    for (int j = 0; j < 9; ++j) mz[j] = *(const uint2*)&mrow[16 * j];
#pragma unroll
    for (int j = 0; j < 9; ++j) {
        uint2 bz = *(const uint2*)&sBias[nb18 * 148 + 16 * j + 4 * quad];
        const _Float16* bb = (const _Float16*)&bz;
        const _Float16* mm = (const _Float16*)&mz[j];
#pragma unroll
        for (int reg = 0; reg < 4; ++reg)
            tj[j][reg] += (float)bb[reg] + (float)mm[reg];
    }
    float rmax = tj[0][0];
#pragma unroll
    for (int j = 0; j < 9; ++j)
#pragma unroll
        for (int reg = 0; reg < 4; ++reg) rmax = fmaxf(rmax, tj[j][reg]);
    rmax = fmaxf(rmax, __shfl_xor(rmax, 16));
    rmax = fmaxf(rmax, __shfl_xor(rmax, 32));
    float rsum = 0.0f;
#pragma unroll
    for (int j = 0; j < 9; ++j)
#pragma unroll
        for (int reg = 0; reg < 4; ++reg) {
            tj[j][reg] = __expf(tj[j][reg] - rmax);
            rsum += tj[j][reg];
        }
    rsum += __shfl_xor(rsum, 16);
    rsum += __shfl_xor(rsum, 32);
    const float inv = 1.0f / rsum;

    // pack P^T rows (scaled) to fp16 pairs; index 9 = zero pad (keys 144..159)
    unsigned int pkA[10], pkB[10];
    pkA[9] = 0u; pkB[9] = 0u;
#pragma unroll
    for (int j = 0; j < 9; ++j) {
        auto a2 = __builtin_amdgcn_cvt_pkrtz(tj[j][0] * inv, tj[j][1] * inv);
        auto b2 = __builtin_amdgcn_cvt_pkrtz(tj[j][2] * inv, tj[j][3] * inv);
        pkA[j] = *(unsigned int*)&a2;
        pkB[j] = *(unsigned int*)&b2;
    }

    // ---- phase 4: O^T = V^T @ P^T ; P^T B-frags via cross-lane shuffles ----
    const int src_lo = 32 * (quad & 1) + l15;
    const int src_hi = src_lo + 16;
    const bool selhi = (quad >> 1) != 0;
    f32x4 o[2] = {};
#pragma unroll
    for (int kt = 0; kt < 5; ++kt) {
        const int j0 = 2 * kt, j1 = 2 * kt + 1;
        unsigned int a0l = __shfl((int)pkA[j0], src_lo);
        unsigned int a1l = __shfl((int)pkA[j1], src_lo);
        unsigned int b0l = __shfl((int)pkB[j0], src_lo);
        unsigned int b1l = __shfl((int)pkB[j1], src_lo);
        unsigned int a0h = __shfl((int)pkA[j0], src_hi);
        unsigned int a1h = __shfl((int)pkA[j1], src_hi);
        unsigned int b0h = __shfl((int)pkB[j0], src_hi);
        unsigned int b1h = __shfl((int)pkB[j1], src_hi);
        union { uint4 u4; half8 h8; } bp;
        bp.u4.x = selhi ? a1l : a0l;
        bp.u4.y = selhi ? b1l : b0l;
        bp.u4.z = selhi ? a1h : a0h;
        bp.u4.w = selhi ? b1h : b0h;
#pragma unroll
        for (int dt = 0; dt < 2; ++dt) {
            const int vrow = dt * 16 + l15;
            half8 av = *(const half8*)&sVT[vrow][(kt * 32 + quad * 8) ^ ((vrow >> 3) << 3)];
            o[dt] = __builtin_amdgcn_mfma_f32_16x16x32_f16(av, bp.h8, o[dt], 0, 0, 0);
        }
    }

    // ---- stores: O^T[d][q] -> AO[b][q][h*32+d] ----
#pragma unroll
    for (int dt = 0; dt < 2; ++dt) {
        int d = dt * 16 + quad * 4;
        half4v hv;
#pragma unroll
        for (int reg = 0; reg < 4; ++reg) hv[reg] = (_Float16)o[dt][reg];
        *(half4v*)&AO[((size_t)b * 144 + q) * 384 + h * 32 + d] = hv;
    }
}

// ---------------------------------------------------------------------------
// K3: out = AO @ WoT^T + b_out. fp32 output. v4 counted-vmcnt pipeline
// (verified passing in round 5).
// ---------------------------------------------------------------------------
#define STAGE3(dA, dB, kk) do {                                   \
    GLD16(gA + (kk),          (char*)(dA) + t * 16);              \
    GLD16(gA + (kk) + 24576,  (char*)(dA) + t * 16 + 4096);       \
    GLD16(gB + (kk),          (char*)(dB) + t * 16);              \
    GLD16(gB + (kk) + 24576,  (char*)(dB) + t * 16 + 4096);       \
} while (0)

#define CSTEP(pA, pB) do {                                        \
    half8 a[4], b[4];                                             \
    _Pragma("unroll")                                             \
    for (int i = 0; i < 4; ++i) a[i] = *(const half8*)((pA) + i * 1024); \
    _Pragma("unroll")                                             \
    for (int j = 0; j < 4; ++j) b[j] = *(const half8*)((pB) + j * 1024); \
    _Pragma("unroll")                                             \
    for (int i = 0; i < 4; ++i)                                   \
    _Pragma("unroll")                                             \
        for (int j = 0; j < 4; ++j)                               \
            acc[i][j] = __builtin_amdgcn_mfma_f32_16x16x32_f16(a[i], b[j], acc[i][j], 0, 0, 0); \
} while (0)

#define GEMM_PIPE() do {                                          \
    STAGE3(sA[0], sB[0], 0);                                      \
    STAGE3(sA[1], sB[1], 32);                                     \
    _Pragma("unroll")                                             \
    for (int s = 0; s < 12; ++s) {                                \
        if (s < 11) { WAITV4; } else { WAITV0; }                  \
        __builtin_amdgcn_s_barrier();                             \
        if (s < 10) STAGE3(sA[(s + 2) % 3], sB[(s + 2) % 3], 32 * (s + 2)); \
        const char* pA = (const char*)sA[s % 3] + aoff;           \
        const char* pB = (const char*)sB[s % 3] + boff;           \
        CSTEP(pA, pB);                                            \
    }                                                             \
} while (0)

__launch_bounds__(256)
__global__ void k_out_gemm_mfma(const _Float16* __restrict__ A16,
                                const _Float16* __restrict__ WoT,
                                const float* __restrict__ bo,
                                float* __restrict__ out) {
    __shared__ __align__(16) _Float16 sA[3][4096];
    __shared__ __align__(16) _Float16 sB[3][4096];
    const int t    = threadIdx.x;
    const int lane = t & 63;
    const int w    = t >> 6;
    const int quad = lane >> 4;
    const int l15  = lane & 15;
    // bijective XCD swizzle: 864 = 8 * 108; col-tile fastest within chunk
    const int bid = blockIdx.x;
    const int wg  = (bid & 7) * 108 + (bid >> 3);
    const int cy  = wg % 3, rx = wg / 3;
    const int r0  = rx * 128, c0 = cy * 128;
    const int wr  = (w >> 1) * 64, wc = (w & 1) * 64;

    const int srow = t >> 2;
    const int skch = (t & 3) ^ ((t >> 3) & 3);
    const _Float16* gA = &A16[(size_t)(r0 + srow) * 384 + skch * 8];
    const _Float16* gB = &WoT[(size_t)(c0 + srow) * 384 + skch * 8];

    const int swz16 = (quad ^ ((l15 >> 1) & 3)) * 16;
    const int aoff  = (wr + l15) * 64 + swz16;
    const int boff  = (wc + l15) * 64 + swz16;

    f32x4 acc[4][4] = {};

    GEMM_PIPE();

#pragma unroll
    for (int j = 0; j < 4; ++j) {
        int c = c0 + wc + 16 * j + l15;
        float bias = bo[c];
#pragma unroll
        for (int i = 0; i < 4; ++i) {
#pragma unroll
            for (int reg = 0; reg < 4; ++reg) {
                int r = r0 + wr + 16 * i + quad * 4 + reg;
                out[(size_t)r * 384 + c] = acc[i][j][reg] + bias;
            }
        }
    }
}

// ---------------------------------------------------------------------------
extern "C" void kernel_launch(void* const* d_in, const int* in_sizes, int n_in,
                              void* d_out, int out_size, void* d_ws, size_t ws_size,
                              hipStream_t stream) {
    const float* x      = (const float*)d_in[0];
    const float* mask   = (const float*)d_in[1];
    const float* w_qkv  = (const float*)d_in[2];
    const float* b_qkv  = (const float*)d_in[3];
    const float* w_out  = (const float*)d_in[4];
    const float* b_out  = (const float*)d_in[5];
    const float* table  = (const float*)d_in[6];
    const int*   pidx   = (const int*)d_in[7];
    float* out = (float*)d_out;
    _Float16* ws16 = (_Float16*)d_ws;

    const bool pre = ws_size >= (size_t)WS_NEED_BYTES;
    _Float16* bias16 = pre ? (ws16 + BIASH) : (_Float16*)nullptr;

    hipLaunchKernelGGL(k_prep,          dim3(pre ? 15426 : 14130), dim3(256), 0, stream,
                       x, ws16 + X16H, w_qkv, ws16 + WTH, w_out, ws16 + WOTH,
                       mask, ws16 + MASKH, table, pidx, bias16);
    hipLaunchKernelGGL(k_fused_qkv_attn, dim3(3072), dim3(576), 0, stream,
                       ws16 + X16H, ws16 + WTH, b_qkv, ws16 + MASKH,
                       table, pidx, bias16, ws16 + QH);
    hipLaunchKernelGGL(k_out_gemm_mfma, dim3(864), dim3(256), 0, stream,
                       ws16 + QH, ws16 + WOTH, b_out, out);
}

// Round 10
// 240.929 us; speedup vs baseline: 1.1099x; 1.0171x over previous
//
#include <hip/hip_runtime.h>
#include <hip/hip_fp16.h>
#include <cstdint>
#include <cstddef>

#define NQQ  (144*144)        // 20736
#define SCALE 0.17677669529663687f

// ws layout in HALF elements.
// X16 [0, 14155776) ; AO [QH, QH+14155776) (must NOT alias X16 — fused kernel
// reads X16 while writing AO).
#define X16H  0ull
#define QH    14155776ull      // = AO region for K3
#define WTH   56623104ull      // 442368 halves (1152x384)
#define WOTH  57065472ull      // 147456 halves (384x384)
#define MASKH 57212928ull      // 165888 halves (8x144x144 fp16)
#define BIASH 57378816ull      // 3072 x 2592 fp16 precomputed bias (optional)
#define WS_NEED_BYTES ((BIASH + 3072ull * 2592ull) * 2ull)

typedef _Float16 half8  __attribute__((ext_vector_type(8)));
typedef _Float16 half4v __attribute__((ext_vector_type(4)));
typedef float    f32x4  __attribute__((ext_vector_type(4)));

typedef __attribute__((address_space(1))) const unsigned int guint;
typedef __attribute__((address_space(3))) unsigned int luint;
#define GLD16(g, l) __builtin_amdgcn_global_load_lds((guint*)(g), (luint*)(l), 16, 0, 0)

#define WAITV4 asm volatile("s_waitcnt vmcnt(4)" ::: "memory")
#define WAITV2 asm volatile("s_waitcnt vmcnt(2)" ::: "memory")
#define WAITV1 asm volatile("s_waitcnt vmcnt(1)" ::: "memory")
#define WAITV0 asm volatile("s_waitcnt vmcnt(0)" ::: "memory")

// ---------------------------------------------------------------------------
// PREP: [0,13824) X fp32->fp16; [13824,13932) transpose w_qkv;
// [13932,13968) transpose w_out; [13968,14130) mask fp32->fp16;
// [14130,15426) OPTIONAL bias precompute (dense fp16 bias[bh][2592]).
// ---------------------------------------------------------------------------
__launch_bounds__(256)
__global__ void k_prep(const float* __restrict__ X, _Float16* __restrict__ X16,
                       const float* __restrict__ Wq, _Float16* __restrict__ WqT,
                       const float* __restrict__ Wo, _Float16* __restrict__ WoT,
                       const float* __restrict__ M, _Float16* __restrict__ M16,
                       const float* __restrict__ table, const int* __restrict__ pidx,
                       _Float16* __restrict__ biasOut) {
    __shared__ __align__(16) char psm[13888];
    const int bid = blockIdx.x;
    const int t   = threadIdx.x;
    if (bid < 13824) {
        size_t i = (size_t)bid * 256 + t;
        float4 f = *(const float4*)&X[i * 4];
        _Float16 h[4] = {(_Float16)f.x, (_Float16)f.y, (_Float16)f.z, (_Float16)f.w};
        *(ushort4*)&X16[i * 4] = *(ushort4*)h;
        return;
    }
    if (bid >= 14130) {
        // ---- bias precompute: block = (s_tile, chunk of 16 i-rows) ----
        _Float16 (*sTb)[18] = (_Float16(*)[18])psm;   // 384 x 18 halves = 13824 B
        int* rowsL = (int*)(psm + 13824);             // 16 ints
        const int j      = bid - 14130;
        const int s_tile = j / 162;
        const int chunk  = j - s_tile * 162;
        const int i0     = chunk * 16;
        if (t < 16) rowsL[t] = pidx[8 * (i0 + t) + s_tile];
        __syncthreads();
#pragma unroll
        for (int rr = 0; rr < 16; ++rr) {
            int row = rowsL[rr];
            sTb[t][rr] = (_Float16)table[(size_t)row * 384 + t];
            if (t < 128) sTb[t + 256][rr] = (_Float16)table[(size_t)row * 384 + t + 256];
        }
        __syncthreads();
        unsigned int* ob = (unsigned int*)biasOut;    // dword view of fp16 pairs
#pragma unroll
        for (int v = t; v < 3072; v += 256) {
            int i1h = v >> 3, dw = v & 7;             // bh = s_tile*384 + i1h
            ob[(size_t)(s_tile * 384 + i1h) * 1296 + chunk * 8 + dw] =
                *(const unsigned int*)&sTb[i1h][dw * 2];
        }
        return;
    }
    if (bid >= 13968) {
        size_t i = (size_t)(bid - 13968) * 256 + t;
        float4 f = *(const float4*)&M[i * 4];
        _Float16 h[4] = {(_Float16)f.x, (_Float16)f.y, (_Float16)f.z, (_Float16)f.w};
        *(ushort4*)&M16[i * 4] = *(ushort4*)h;
        return;
    }
    _Float16 (*sT)[72] = (_Float16(*)[72])psm;        // 64 x 72 halves = 9216 B
    const float* W; _Float16* WT; int K, Cn, cb, kb;
    if (bid < 13932) {
        int j = bid - 13824;
        W = Wq; WT = WqT; K = 384; Cn = 1152;
        cb = (j % 18) * 64; kb = (j / 18) * 64;
    } else {
        int j = bid - 13932;
        W = Wo; WT = WoT; K = 384; Cn = 384;
        cb = (j % 6) * 64; kb = (j / 6) * 64;
    }
#pragma unroll
    for (int i = 0; i < 16; ++i) {
        int id = t + 256 * i;
        int kl = id >> 6, cl = id & 63;
        sT[cl][kl] = (_Float16)W[(size_t)(kb + kl) * Cn + cb + cl];
    }
    __syncthreads();
#pragma unroll
    for (int i = 0; i < 16; ++i) {
        int id = t + 256 * i;
        int cl = id >> 6, kl = id & 63;
        WT[(size_t)(cb + cl) * K + kb + kl] = sT[cl][kl];
    }
}

// ---------------------------------------------------------------------------
// FUSED K1+K2: per (b,h) block — QKV GEMM (144x96 = X16[b] @ Wh^T), epilogue
// straight into LDS attn layouts (sQ/sK/sVT), then the verified attn phases
// 2-4. QKV never touches HBM.
// v4 of the fusion: layout = round-8 VERIFIED (srB fix); GEMM schedule =
// 3-buffer counted-vmcnt pipeline (T4). Rounds 6/7 proved the failure was the
// srow&95 layout bug (bit-identical absmax across two schedules), not the
// counted-vmcnt schedule. Per-wave waits are wave-uniform: waves 0-5 issue
// 2 GLD16/stage -> vmcnt(2); waves 6-8 issue 1 -> vmcnt(1); loads stay in
// flight ACROSS barriers (drain to 0 only at the last step).
// LDS 51408 B: A bufs [0,27648) x3, B bufs [27648,46080) x3;
// aliased post-GEMM: sQ [0,11520) sK [11520,23040) sVT [23040,33792);
// sBias [46080,51408).
// ---------------------------------------------------------------------------
__launch_bounds__(576)
__global__ void k_fused_qkv_attn(const _Float16* __restrict__ X16,
                                 const _Float16* __restrict__ WT,
                                 const float* __restrict__ bq,
                                 const _Float16* __restrict__ mask16,
                                 const float* __restrict__ table,
                                 const int* __restrict__ pidx,
                                 const _Float16* __restrict__ bias_pre,
                                 _Float16* __restrict__ AO) {
    __shared__ __align__(16) char smem[51408];
    char* sAb = smem;                    // 3 x 9216
    char* sBb = smem + 27648;            // 3 x 6144
    _Float16 (*sQ)[40]   = (_Float16(*)[40])(smem);
    _Float16 (*sK)[40]   = (_Float16(*)[40])(smem + 11520);
    _Float16 (*sVT)[168] = (_Float16(*)[168])(smem + 23040);
    _Float16* sBias      = (_Float16*)(smem + 46080);  // 18*148*2 = 5328

    const int bid = blockIdx.x;
    const int wg  = (bid & 7) * 384 + (bid >> 3);  // 3072 = 8*384: same-b -> same XCD
    const int b   = wg / 12;
    const int h   = wg - b * 12;
    const int t   = threadIdx.x;
    const int w    = t >> 6;        // 0..8 : q-tile index / GEMM row-tile
    const int lane = t & 63;
    const int quad = lane >> 4;
    const int l15  = lane & 15;

    const int s_tile = b >> 5;
    const int i1     = b & 31;

    // staging geometry (identical swizzle family to the verified v2/v4 GEMMs)
    const int srow = t >> 2;                       // A: 144 rows x 4 chunks = 576
    const int schk = (t & 3) ^ ((t >> 3) & 3);     // inverse-swizzled source chunk
    const _Float16* gA = &X16[((size_t)b * 144 + srow) * 384 + schk * 8];
    const int srB  = (srow < 96) ? srow : 0;       // B: 96 rows (t<384 stage it)
    const int prow = (srB >> 5) * 384 + h * 32 + (srB & 31);
    const _Float16* gB = &WT[(size_t)prow * 384 + schk * 8];
    const int swz16 = (quad ^ ((l15 >> 1) & 3)) * 16;
    const int aoff  = (16 * w + l15) * 64 + swz16;

    // ---- prologue: bias -> sBias (vmcnt drained before the counted loop) ----
    if (bias_pre) {
        const _Float16* bg = bias_pre + (size_t)wg * 2592;
        for (int i2 = t; i2 < 648; i2 += 576) {
            uint2 wv = *(const uint2*)&bg[i2 * 4];
            int r18 = i2 / 36;
            int col = i2 * 4 - r18 * 144;
            *(uint2*)&sBias[r18 * 148 + col] = wv;
        }
    } else {
        for (int i = t; i < 2592; i += 576) {
            int row = pidx[8 * i + s_tile];
            int r18 = i / 144;
            sBias[r18 * 148 + (i - r18 * 144)] =
                (_Float16)table[(size_t)row * 384 + i1 * 12 + h];
        }
    }
    WAITV0;   // bias loads must not pollute the counted vmcnt window

    // ---- GEMM: acc[j] = D[row=16w+quad*4+reg][col=16j+l15], j=0..5 ----
    f32x4 acc[6] = {};
#define FSTG(s_) do {                                                      \
        GLD16(gA + 32 * (s_), sAb + ((s_) % 3) * 9216 + t * 16);           \
        if (t < 384) GLD16(gB + 32 * (s_), sBb + ((s_) % 3) * 6144 + t * 16); \
    } while (0)
    FSTG(0); FSTG(1);
#pragma unroll
    for (int s = 0; s < 12; ++s) {
        if (s < 11) {
            if (w < 6) { WAITV2; } else { WAITV1; }   // stage s landed; s+1 in flight
        } else { WAITV0; }
        __builtin_amdgcn_s_barrier();
        if (s < 10) FSTG(s + 2);
        const char* pA = sAb + (s % 3) * 9216 + aoff;
        half8 av = *(const half8*)pA;
        const char* pB = sBb + (s % 3) * 6144;
#pragma unroll
        for (int j = 0; j < 6; ++j) {
            half8 bv = *(const half8*)(pB + (16 * j + l15) * 64 + swz16);
            acc[j] = __builtin_amdgcn_mfma_f32_16x16x32_f16(av, bv, acc[j], 0, 0, 0);
        }
    }
#undef FSTG
    __syncthreads();   // all dbuf reads done before aliased epilogue writes

    // ---- epilogue: QKV -> LDS attn layouts (+bias, Q scaled) ----
    float bqv[6];
#pragma unroll
    for (int j = 0; j < 6; ++j)
        bqv[j] = bq[(j >> 1) * 384 + h * 32 + (j & 1) * 16 + l15];
    const int erow = 16 * w + quad * 4;
#pragma unroll
    for (int j = 0; j < 2; ++j)
#pragma unroll
        for (int reg = 0; reg < 4; ++reg)
            sQ[erow + reg][16 * j + l15] = (_Float16)((acc[j][reg] + bqv[j]) * SCALE);
#pragma unroll
    for (int j = 0; j < 2; ++j)
#pragma unroll
        for (int reg = 0; reg < 4; ++reg)
            sK[erow + reg][16 * j + l15] = (_Float16)(acc[2 + j][reg] + bqv[2 + j]);
#pragma unroll
    for (int j = 0; j < 2; ++j) {
        const int d   = 16 * j + l15;
        const int dsw = (d >> 3) << 3;
#pragma unroll
        for (int reg = 0; reg < 4; ++reg)
            sVT[d][(erow + reg) ^ dsw] = (_Float16)(acc[4 + j][reg] + bqv[4 + j]);
    }
    if (t < 512) {                                 // V^T zero-pad cols 144..159
        int d = t & 31, m = 144 + (t >> 5);
        sVT[d][m ^ ((d >> 3) << 3)] = (_Float16)0;
    }
    __syncthreads();

    // ---- phase 2: T_j = S^T tiles = mfma(K_j, Q_w) ----
    half8 aq = *(const half8*)&sQ[16 * w + l15][quad * 8];
    f32x4 tj[9] = {};
#pragma unroll
    for (int j = 0; j < 9; ++j) {
        half8 bk = *(const half8*)&sK[16 * j + l15][quad * 8];
        tj[j] = __builtin_amdgcn_mfma_f32_16x16x32_f16(bk, aq, tj[j], 0, 0, 0);
    }

    // ---- phase 3: bias + mask + softmax over each query column ----
    const int q    = 16 * w + l15;
    const int nb18 = q % 18;
    const _Float16* mrow = mask16 + (size_t)(b & 7) * NQQ + (size_t)q * 144 + 4 * quad;
    uint2 mz[9];
#pragma unroll
    for (int j = 0; j < 9; ++j) mz[j] = *(const uint2*)&mrow[16 * j];
#pragma unroll
    for (int j = 0; j < 9; ++j) {
        uint2 bz = *(const uint2*)&sBias[nb18 * 148 + 16 * j + 4 * quad];
        const _Float16* bb = (const _Float16*)&bz;
        const _Float16* mm = (const _Float16*)&mz[j];
#pragma unroll
        for (int reg = 0; reg < 4; ++reg)
            tj[j][reg] += (float)bb[reg] + (float)mm[reg];
    }
    float rmax = tj[0][0];
#pragma unroll
    for (int j = 0; j < 9; ++j)
#pragma unroll
        for (int reg = 0; reg < 4; ++reg) rmax = fmaxf(rmax, tj[j][reg]);
    rmax = fmaxf(rmax, __shfl_xor(rmax, 16));
    rmax = fmaxf(rmax, __shfl_xor(rmax, 32));
    float rsum = 0.0f;
#pragma unroll
    for (int j = 0; j < 9; ++j)
#pragma unroll
        for (int reg = 0; reg < 4; ++reg) {
            tj[j][reg] = __expf(tj[j][reg] - rmax);
            rsum += tj[j][reg];
        }
    rsum += __shfl_xor(rsum, 16);
    rsum += __shfl_xor(rsum, 32);
    const float inv = 1.0f / rsum;

    // pack P^T rows (scaled) to fp16 pairs; index 9 = zero pad (keys 144..159)
    unsigned int pkA[10], pkB[10];
    pkA[9] = 0u; pkB[9] = 0u;
#pragma unroll
    for (int j = 0; j < 9; ++j) {
        auto a2 = __builtin_amdgcn_cvt_pkrtz(tj[j][0] * inv, tj[j][1] * inv);
        auto b2 = __builtin_amdgcn_cvt_pkrtz(tj[j][2] * inv, tj[j][3] * inv);
        pkA[j] = *(unsigned int*)&a2;
        pkB[j] = *(unsigned int*)&b2;
    }

    // ---- phase 4: O^T = V^T @ P^T ; P^T B-frags via cross-lane shuffles ----
    const int src_lo = 32 * (quad & 1) + l15;
    const int src_hi = src_lo + 16;
    const bool selhi = (quad >> 1) != 0;
    f32x4 o[2] = {};
#pragma unroll
    for (int kt = 0; kt < 5; ++kt) {
        const int j0 = 2 * kt, j1 = 2 * kt + 1;
        unsigned int a0l = __shfl((int)pkA[j0], src_lo);
        unsigned int a1l = __shfl((int)pkA[j1], src_lo);
        unsigned int b0l = __shfl((int)pkB[j0], src_lo);
        unsigned int b1l = __shfl((int)pkB[j1], src_lo);
        unsigned int a0h = __shfl((int)pkA[j0], src_hi);
        unsigned int a1h = __shfl((int)pkA[j1], src_hi);
        unsigned int b0h = __shfl((int)pkB[j0], src_hi);
        unsigned int b1h = __shfl((int)pkB[j1], src_hi);
        union { uint4 u4; half8 h8; } bp;
        bp.u4.x = selhi ? a1l : a0l;
        bp.u4.y = selhi ? b1l : b0l;
        bp.u4.z = selhi ? a1h : a0h;
        bp.u4.w = selhi ? b1h : b0h;
#pragma unroll
        for (int dt = 0; dt < 2; ++dt) {
            const int vrow = dt * 16 + l15;
            half8 av = *(const half8*)&sVT[vrow][(kt * 32 + quad * 8) ^ ((vrow >> 3) << 3)];
            o[dt] = __builtin_amdgcn_mfma_f32_16x16x32_f16(av, bp.h8, o[dt], 0, 0, 0);
        }
    }

    // ---- stores: O^T[d][q] -> AO[b][q][h*32+d] ----
#pragma unroll
    for (int dt = 0; dt < 2; ++dt) {
        int d = dt * 16 + quad * 4;
        half4v hv;
#pragma unroll
        for (int reg = 0; reg < 4; ++reg) hv[reg] = (_Float16)o[dt][reg];
        *(half4v*)&AO[((size_t)b * 144 + q) * 384 + h * 32 + d] = hv;
    }
}

// ---------------------------------------------------------------------------
// K3: out = AO @ WoT^T + b_out. fp32 output. v4 counted-vmcnt pipeline
// (verified passing in rounds 5/8).
// ---------------------------------------------------------------------------
#define STAGE3(dA, dB, kk) do {                                   \
    GLD16(gA + (kk),          (char*)(dA) + t * 16);              \
    GLD16(gA + (kk) + 24576,  (char*)(dA) + t * 16 + 4096);       \
    GLD16(gB + (kk),          (char*)(dB) + t * 16);              \
    GLD16(gB + (kk) + 24576,  (char*)(dB) + t * 16 + 4096);       \
} while (0)

#define CSTEP(pA, pB) do {                                        \
    half8 a[4], b[4];                                             \
    _Pragma("unroll")                                             \
    for (int i = 0; i < 4; ++i) a[i] = *(const half8*)((pA) + i * 1024); \
    _Pragma("unroll")                                             \
    for (int j = 0; j < 4; ++j) b[j] = *(const half8*)((pB) + j * 1024); \
    _Pragma("unroll")                                             \
    for (int i = 0; i < 4; ++i)                                   \
    _Pragma("unroll")                                             \
        for (int j = 0; j < 4; ++j)                               \
            acc[i][j] = __builtin_amdgcn_mfma_f32_16x16x32_f16(a[i], b[j], acc[i][j], 0, 0, 0); \
} while (0)

#define GEMM_PIPE() do {                                          \
    STAGE3(sA[0], sB[0], 0);                                      \
    STAGE3(sA[1], sB[1], 32);                                     \
    _Pragma("unroll")                                             \
    for (int s = 0; s < 12; ++s) {                                \
        if (s < 11) { WAITV4; } else { WAITV0; }                  \
        __builtin_amdgcn_s_barrier();                             \
        if (s < 10) STAGE3(sA[(s + 2) % 3], sB[(s + 2) % 3], 32 * (s + 2)); \
        const char* pA = (const char*)sA[s % 3] + aoff;           \
        const char* pB = (const char*)sB[s % 3] + boff;           \
        CSTEP(pA, pB);                                            \
    }                                                             \
} while (0)

__launch_bounds__(256)
__global__ void k_out_gemm_mfma(const _Float16* __restrict__ A16,
                                const _Float16* __restrict__ WoT,
                                const float* __restrict__ bo,
                                float* __restrict__ out) {
    __shared__ __align__(16) _Float16 sA[3][4096];
    __shared__ __align__(16) _Float16 sB[3][4096];
    const int t    = threadIdx.x;
    const int lane = t & 63;
    const int w    = t >> 6;
    const int quad = lane >> 4;
    const int l15  = lane & 15;
    // bijective XCD swizzle: 864 = 8 * 108; col-tile fastest within chunk
    const int bid = blockIdx.x;
    const int wg  = (bid & 7) * 108 + (bid >> 3);
    const int cy  = wg % 3, rx = wg / 3;
    const int r0  = rx * 128, c0 = cy * 128;
    const int wr  = (w >> 1) * 64, wc = (w & 1) * 64;

    const int srow = t >> 2;
    const int skch = (t & 3) ^ ((t >> 3) & 3);
    const _Float16* gA = &A16[(size_t)(r0 + srow) * 384 + skch * 8];
    const _Float16* gB = &WoT[(size_t)(c0 + srow) * 384 + skch * 8];

    const int swz16 = (quad ^ ((l15 >> 1) & 3)) * 16;
    const int aoff  = (wr + l15) * 64 + swz16;
    const int boff  = (wc + l15) * 64 + swz16;

    f32x4 acc[4][4] = {};

    GEMM_PIPE();

#pragma unroll
    for (int j = 0; j < 4; ++j) {
        int c = c0 + wc + 16 * j + l15;
        float bias = bo[c];
#pragma unroll
        for (int i = 0; i < 4; ++i) {
#pragma unroll
            for (int reg = 0; reg < 4; ++reg) {
                int r = r0 + wr + 16 * i + quad * 4 + reg;
                out[(size_t)r * 384 + c] = acc[i][j][reg] + bias;
            }
        }
    }
}

// ---------------------------------------------------------------------------
extern "C" void kernel_launch(void* const* d_in, const int* in_sizes, int n_in,
                              void* d_out, int out_size, void* d_ws, size_t ws_size,
                              hipStream_t stream) {
    const float* x      = (const float*)d_in[0];
    const float* mask   = (const float*)d_in[1];
    const float* w_qkv  = (const float*)d_in[2];
    const float* b_qkv  = (const float*)d_in[3];
    const float* w_out  = (const float*)d_in[4];
    const float* b_out  = (const float*)d_in[5];
    const float* table  = (const float*)d_in[6];
    const int*   pidx   = (const int*)d_in[7];
    float* out = (float*)d_out;
    _Float16* ws16 = (_Float16*)d_ws;

    const bool pre = ws_size >= (size_t)WS_NEED_BYTES;
    _Float16* bias16 = pre ? (ws16 + BIASH) : (_Float16*)nullptr;

    hipLaunchKernelGGL(k_prep,          dim3(pre ? 15426 : 14130), dim3(256), 0, stream,
                       x, ws16 + X16H, w_qkv, ws16 + WTH, w_out, ws16 + WOTH,
                       mask, ws16 + MASKH, table, pidx, bias16);
    hipLaunchKernelGGL(k_fused_qkv_attn, dim3(3072), dim3(576), 0, stream,
                       ws16 + X16H, ws16 + WTH, b_qkv, ws16 + MASKH,
                       table, pidx, bias16, ws16 + QH);
    hipLaunchKernelGGL(k_out_gemm_mfma, dim3(864), dim3(256), 0, stream,
                       ws16 + QH, ws16 + WOTH, b_out, out);
}